// Round 12
// baseline (360.493 us; speedup 1.0000x reference)
//
#include <hip/hip_runtime.h>

#define SEQ    2048
#define DIMK   1024
#define NQKV   3072
#define HEADS  16
#define DHEAD  64
#define HALFD  32
#define MROWS  4096
#define BHN    32
#define PER_MAT (BHN*SEQ*DHEAD)    // 4,194,304
#define QSCALE 0.18033688f         // 0.125 * log2(e): folded so attn uses exp2
#define NTHETA -0.415241002f       // -log2(10000)/32

typedef short bf16x8 __attribute__((ext_vector_type(8)));
typedef float f32x4  __attribute__((ext_vector_type(4)));

__device__ __forceinline__ float bf2f(unsigned short u) {
    return __uint_as_float(((unsigned int)u) << 16);
}
__device__ __forceinline__ unsigned short f2bf(float f) {
    unsigned int x = __float_as_uint(f);
    unsigned int r = (x + 0x7FFFu + ((x >> 16) & 1u)) >> 16;   // RNE
    return (unsigned short)r;
}
// async global->LDS, 16 B per lane; LDS dest = wave-uniform base + lane*16
__device__ __forceinline__ void gload16(const unsigned short* g, unsigned short* l) {
    __builtin_amdgcn_global_load_lds((const __attribute__((address_space(1))) void*)g,
                                     (__attribute__((address_space(3))) void*)l,
                                     16, 0, 0);
}

// ---------------------------------------------------------------------------
// Fused prep: [0,4096) X fp32->bf16 | [4096,7168) Wqkv T+cvt | [7168,8192) Wout
// ---------------------------------------------------------------------------
__global__ __launch_bounds__(256) void prep(const float* __restrict__ X,
                                            unsigned short* __restrict__ Xb,
                                            const float* __restrict__ Wq,
                                            unsigned short* __restrict__ Wqt,
                                            const float* __restrict__ Wo,
                                            unsigned short* __restrict__ Wot) {
    __shared__ float tile[32][33];
    const int b = blockIdx.x, t = threadIdx.x;
    if (b < 4096) {
        const int i = (b * 256 + t) * 4;
        float4 v = *(const float4*)&X[i];
        ushort4 o;
        o.x = f2bf(v.x); o.y = f2bf(v.y); o.z = f2bf(v.z); o.w = f2bf(v.w);
        *(ushort4*)&Xb[i] = o;
        return;
    }
    const float* in; unsigned short* out; int C, bx, by;
    if (b < 7168) {
        const int id = b - 4096;              // 96 x 32 tiles
        in = Wq; out = Wqt; C = NQKV;
        bx = (id % 96) * 32; by = (id / 96) * 32;
    } else {
        const int id = b - 7168;              // 32 x 32 tiles
        in = Wo; out = Wot; C = DIMK;
        bx = (id & 31) * 32; by = (id >> 5) * 32;
    }
    const int tx = t & 31, ty = t >> 5;       // 32 x 8
    #pragma unroll
    for (int i = 0; i < 32; i += 8)
        tile[ty + i][tx] = in[(by + ty + i) * C + bx + tx];
    __syncthreads();
    #pragma unroll
    for (int i = 0; i < 32; i += 8)
        out[(bx + ty + i) * DIMK + by + tx] = f2bf(tile[tx][ty + i]);
}

// ---------------------------------------------------------------------------
// MFMA GEMM1 + fused RoPE (sincos recurrence) + fused V-transpose.
// 128x128 tile, BK=32, m97 staging. (256,3): grid 768 = 3/CU co-resident.
// V stored transposed AND key-pair-permuted: within each 32-token block,
// position 8*quad + 4*b + r  holds token 16*b + 4*quad + r  -- so the
// attention kernel's contiguous b128 V read yields the exact B-frag key
// order forced by S^T's C-layout (keys split 4|4 across two 16-tiles).
// ---------------------------------------------------------------------------
__global__ __launch_bounds__(256, 3) void gemm_qkv(const unsigned short* __restrict__ A,
                                                   const unsigned short* __restrict__ Bt,
                                                   unsigned short* __restrict__ QKV) {
    __shared__ __align__(16) unsigned short As[128 * 32];   // [row][k], flat
    __shared__ __align__(16) unsigned short Bs[128 * 32];
    const int t = threadIdx.x;
    const int m0 = blockIdx.y * 128, n0 = blockIdx.x * 128;
    const int w = t >> 6, lane = t & 63;
    const int wr = (w >> 1) * 64, wc = (w & 1) * 64;
    const int l15 = lane & 15, quad = lane >> 4;
    const int arow = t >> 2, acol = (t & 3) * 8;   // 8 elems = 16 B per lane

    f32x4 acc[4][4];
    #pragma unroll
    for (int i = 0; i < 4; ++i)
        #pragma unroll
        for (int j = 0; j < 4; ++j) acc[i][j] = (f32x4){0.f, 0.f, 0.f, 0.f};

    for (int k0 = 0; k0 < DIMK; k0 += 32) {
        __syncthreads();
        gload16(&A [(m0 + arow)      * DIMK + k0 + acol], &As[t * 8]);
        gload16(&A [(m0 + 64 + arow) * DIMK + k0 + acol], &As[2048 + t * 8]);
        gload16(&Bt[(n0 + arow)      * DIMK + k0 + acol], &Bs[t * 8]);
        gload16(&Bt[(n0 + 64 + arow) * DIMK + k0 + acol], &Bs[2048 + t * 8]);
        __syncthreads();
        bf16x8 af[4], bf[4];
        #pragma unroll
        for (int i = 0; i < 4; ++i) af[i] = *(const bf16x8*)&As[(wr + i * 16 + l15) * 32 + quad * 8];
        #pragma unroll
        for (int j = 0; j < 4; ++j) bf[j] = *(const bf16x8*)&Bs[(wc + j * 16 + l15) * 32 + quad * 8];
        #pragma unroll
        for (int i = 0; i < 4; ++i)
            #pragma unroll
            for (int j = 0; j < 4; ++j)
                acc[i][j] = __builtin_amdgcn_mfma_f32_16x16x32_bf16(af[i], bf[j], acc[i][j], 0, 0, 0);
    }

    const int which = n0 >> 10;                    // uniform per block
    const int h     = ((n0 & 1023) + wc) >> 6;     // uniform per wave-half
    const int bb    = (m0 + wr) >> 11;             // batch, constant per wave-half
    const int bh    = bb * HEADS + h;
    if (which == 2) {
        // V -> Vp [bh][d][key-paired], one ushort4 per (i,j) at permuted pos
        #pragma unroll
        for (int i = 0; i < 4; ++i) {
            const int pos = ((m0 + wr) & 2047) + 32 * (i >> 1) + quad * 8 + ((i & 1) << 2);
            #pragma unroll
            for (int j = 0; j < 4; ++j) {
                const int d = j * 16 + l15;
                ushort4 o;
                o.x = f2bf(acc[i][j][0]); o.y = f2bf(acc[i][j][1]);
                o.z = f2bf(acc[i][j][2]); o.w = f2bf(acc[i][j][3]);
                *(ushort4*)&QKV[2 * PER_MAT + (bh * DHEAD + d) * SEQ + pos] = o;
            }
        }
    } else {
        const float qs = (which == 0) ? QSCALE : 1.0f;
        const int nb = ((m0 + wr) & 2047) + quad * 4;   // row base for r=0,i=0
        #pragma unroll
        for (int j = 0; j < 2; ++j) {                   // d in [0,32): pair at d+32
            const int d = j * 16 + l15;
            const float theta = exp2f((float)d * NTHETA);
            float s1, c1, s16, c16, si, ci;
            sincosf(theta, &s1, &c1);                   // step-1 rotation (fast path)
            sincosf(16.0f * theta, &s16, &c16);         // step-16 rotation
            sincosf((float)nb * theta, &si, &ci);       // base angle (slow path, once)
            #pragma unroll
            for (int i = 0; i < 4; ++i) {
                float cr = ci, sr = si;
                #pragma unroll
                for (int r = 0; r < 4; ++r) {
                    const int n = nb + i * 16 + r;
                    const float x1 = acc[i][j][r], x2 = acc[i][j + 2][r];
                    const int base = which * PER_MAT + (bh * SEQ + n) * DHEAD;
                    QKV[base + d]         = f2bf((x1 * cr - x2 * sr) * qs);
                    QKV[base + d + HALFD] = f2bf((x1 * sr + x2 * cr) * qs);
                    const float crn = cr * c1 - sr * s1;
                    sr = sr * c1 + cr * s1; cr = crn;   // advance by theta
                }
                const float cin = ci * c16 - si * s16;
                si = si * c16 + ci * s16; ci = cin;     // advance by 16*theta
            }
        }
    }
}

// ---------------------------------------------------------------------------
// LDS-FREE MFMA flash attention. All MFMA operand frags are contiguous 16B
// chunks in global (K [bh][key][d], Vp [bh][d][key-paired]) consumed in full
// cache lines; per-bh K+V = 512 KB lives in XCD L2. No __shared__, no
// barriers -> loads pipeline freely through exp2/PV.
// S^T = mfma(A=K, B=Q); P=2^S packed in regs; l via ones-row MFMA.
// Block: 64 q (4 independent waves x 16 q); K-tiles of 64 keys.
// ---------------------------------------------------------------------------
__global__ __launch_bounds__(256, 4) void attn_mfma(const unsigned short* __restrict__ QKV,
                                                    unsigned short* __restrict__ AO) {
    const int t = threadIdx.x, w = t >> 6, lane = t & 63;
    const int l15 = lane & 15, quad = lane >> 4;
    const int bh = blockIdx.y, q0 = blockIdx.x * 64;
    const unsigned short* Qp = QKV;              // pre-roped, pre-scaled
    const unsigned short* Kp = QKV + PER_MAT;    // pre-roped, [bh][key][d]
    const unsigned short* Vp = QKV + 2 * PER_MAT;// [bh][d][key-paired]

    // Q B-operand frag: [n=q=l15][k=d=quad*8+j]
    bf16x8 qf[2];
    #pragma unroll
    for (int ks = 0; ks < 2; ++ks)
        qf[ks] = *(const bf16x8*)&Qp[(bh * SEQ + q0 + w * 16 + l15) * DHEAD + ks * 32 + quad * 8];

    const bf16x8 ones = {(short)0x3F80, (short)0x3F80, (short)0x3F80, (short)0x3F80,
                         (short)0x3F80, (short)0x3F80, (short)0x3F80, (short)0x3F80};

    f32x4 O[4];        // O^T: row=d=dt*16+quad*4+r, col=q=l15
    f32x4 Ol;          // l accumulator (ones-row MFMA), col=q=l15
    #pragma unroll
    for (int dt = 0; dt < 4; ++dt) O[dt] = (f32x4){0.f, 0.f, 0.f, 0.f};
    Ol = (f32x4){0.f, 0.f, 0.f, 0.f};

    // per-lane global bases: K frag A[m=key][k=d], V frag A[m=d][k=key-paired]
    const unsigned short* kb = &Kp[(bh * SEQ + l15) * DHEAD + quad * 8];
    const unsigned short* vb = &Vp[(bh * DHEAD + l15) * SEQ + quad * 8];

    for (int kt = 0; kt < SEQ; kt += 64) {
        // S^T tiles: S[nt], keys nt*16+quad*4+r, q = l15
        f32x4 S[4];
        #pragma unroll
        for (int nt = 0; nt < 4; ++nt) S[nt] = (f32x4){0.f, 0.f, 0.f, 0.f};
        #pragma unroll
        for (int ks = 0; ks < 2; ++ks)
            #pragma unroll
            for (int nt = 0; nt < 4; ++nt) {
                bf16x8 kf = *(const bf16x8*)&kb[(kt + nt * 16) * DHEAD + ks * 32];
                S[nt] = __builtin_amdgcn_mfma_f32_16x16x32_bf16(kf, qf[ks], S[nt], 0, 0, 0);
            }

        // p = 2^s in regs; pack pairs; l via ones-row MFMA; PV MFMA
        #pragma unroll
        for (int p = 0; p < 2; ++p) {
            unsigned int u[8];
            #pragma unroll
            for (int r = 0; r < 4; ++r) {
                u[r]     = __float_as_uint(__builtin_amdgcn_exp2f(S[2 * p][r]))     + 0x8000u;
                u[4 + r] = __float_as_uint(__builtin_amdgcn_exp2f(S[2 * p + 1][r])) + 0x8000u;
            }
            uint4 pk;
            pk.x = (u[0] >> 16) | (u[1] & 0xFFFF0000u);
            pk.y = (u[2] >> 16) | (u[3] & 0xFFFF0000u);
            pk.z = (u[4] >> 16) | (u[5] & 0xFFFF0000u);
            pk.w = (u[6] >> 16) | (u[7] & 0xFFFF0000u);
            bf16x8 pf = __builtin_bit_cast(bf16x8, pk);
            Ol = __builtin_amdgcn_mfma_f32_16x16x32_bf16(ones, pf, Ol, 0, 0, 0);
            #pragma unroll
            for (int dt = 0; dt < 4; ++dt) {
                bf16x8 vf = *(const bf16x8*)&vb[(dt * 16) * SEQ + kt + p * 32];
                O[dt] = __builtin_amdgcn_mfma_f32_16x16x32_bf16(vf, pf, O[dt], 0, 0, 0);
            }
        }
    }

    const int bb = bh >> 4, h = bh & 15;
    const float inv = 1.f / Ol[0];          // all 4 regs hold the same l
    const int q = q0 + w * 16 + l15;
    #pragma unroll
    for (int dt = 0; dt < 4; ++dt) {
        ushort4 o;
        o.x = f2bf(O[dt][0] * inv); o.y = f2bf(O[dt][1] * inv);
        o.z = f2bf(O[dt][2] * inv); o.w = f2bf(O[dt][3] * inv);
        *(ushort4*)&AO[(bb * SEQ + q) * DIMK + h * DHEAD + dt * 16 + quad * 4] = o;
    }
}

// ---------------------------------------------------------------------------
// MFMA GEMM2: OUT = AO @ Wot^T + bias (fp32 out). Tile 64x128, grid 512.
// ---------------------------------------------------------------------------
__global__ __launch_bounds__(256, 2) void gemm_out(const unsigned short* __restrict__ A,
                                                   const unsigned short* __restrict__ Bt,
                                                   const float* __restrict__ bias,
                                                   float* __restrict__ OUT) {
    __shared__ __align__(16) unsigned short As[64 * 32];
    __shared__ __align__(16) unsigned short Bs[128 * 32];
    const int t = threadIdx.x;
    const int m0 = blockIdx.y * 64, n0 = blockIdx.x * 128;
    const int w = t >> 6, lane = t & 63;
    const int wr = (w >> 1) * 32, wc = (w & 1) * 64;
    const int l15 = lane & 15, quad = lane >> 4;
    const int arow = t >> 2, acol = (t & 3) * 8;

    f32x4 acc[2][4];
    #pragma unroll
    for (int i = 0; i < 2; ++i)
        #pragma unroll
        for (int j = 0; j < 4; ++j) acc[i][j] = (f32x4){0.f, 0.f, 0.f, 0.f};

    for (int k0 = 0; k0 < DIMK; k0 += 32) {
        __syncthreads();
        gload16(&A [(m0 + arow)      * DIMK + k0 + acol], &As[t * 8]);
        gload16(&Bt[(n0 + arow)      * DIMK + k0 + acol], &Bs[t * 8]);
        gload16(&Bt[(n0 + 64 + arow) * DIMK + k0 + acol], &Bs[2048 + t * 8]);
        __syncthreads();
        bf16x8 af[2], bf[4];
        #pragma unroll
        for (int i = 0; i < 2; ++i) af[i] = *(const bf16x8*)&As[(wr + i * 16 + l15) * 32 + quad * 8];
        #pragma unroll
        for (int j = 0; j < 4; ++j) bf[j] = *(const bf16x8*)&Bs[(wc + j * 16 + l15) * 32 + quad * 8];
        #pragma unroll
        for (int i = 0; i < 2; ++i)
            #pragma unroll
            for (int j = 0; j < 4; ++j)
                acc[i][j] = __builtin_amdgcn_mfma_f32_16x16x32_bf16(af[i], bf[j], acc[i][j], 0, 0, 0);
    }

    #pragma unroll
    for (int i = 0; i < 2; ++i) {
        #pragma unroll
        for (int j = 0; j < 4; ++j) {
            const int n = n0 + wc + j * 16 + l15;
            const float bn = bias[n];
            #pragma unroll
            for (int r = 0; r < 4; ++r) {
                const int m = m0 + wr + i * 16 + quad * 4 + r;
                OUT[m * DIMK + n] = acc[i][j][r] + bn;
            }
        }
    }
}

extern "C" void kernel_launch(void* const* d_in, const int* in_sizes, int n_in,
                              void* d_out, int out_size, void* d_ws, size_t ws_size,
                              hipStream_t stream) {
    const float* x     = (const float*)d_in[0];
    const float* w_qkv = (const float*)d_in[1];
    const float* w_out = (const float*)d_in[2];
    const float* b_out = (const float*)d_in[3];
    float* out = (float*)d_out;

    unsigned short* ws  = (unsigned short*)d_ws;
    unsigned short* Xb   = ws;                       // 4,194,304
    unsigned short* Wqt  = Xb   + 4194304;           // 3,145,728
    unsigned short* Wot  = Wqt  + 3145728;           // 1,048,576
    unsigned short* QKVb = Wot  + 1048576;           // 12,582,912 (Q | K | Vp)
    unsigned short* AO   = QKVb + 12582912;          // 4,194,304  (total ~50 MB)

    prep     <<<8192, 256, 0, stream>>>(x, Xb, w_qkv, Wqt, w_out, Wot);
    gemm_qkv <<<dim3(NQKV / 128, MROWS / 128), 256, 0, stream>>>(Xb, Wqt, QKVb);
    attn_mfma<<<dim3(SEQ / 64, BHN), 256, 0, stream>>>(QKVb, AO);
    gemm_out <<<dim3(DIMK / 128, MROWS / 64), 256, 0, stream>>>(AO, Wot, b_out, out);
}